// Round 2
// baseline (954.540 us; speedup 1.0000x reference)
//
#include <hip/hip_runtime.h>

// Problem constants (fixed by setup_inputs)
#define BB 8
#define DD 32
#define HH 512
#define WW 512
#define HWSZ (HH*WW)          // 262144 = 2^18
#define NPIX (BB*HWSZ)        // 2097152
#define CC 19
#define EPSF 1e-8f

// Accumulator layout: per class 65 floats: [0..31]=sum(x), [32..63]=sum(x/|x|), [64]=count
#define CSTRIDE 65
#define ACCSZ (CC*CSTRIDE)    // 1235 floats = 4940 B  (total ws footprint)
#define NCOPY 4               // LDS copies to cut bank/same-address conflicts

#define NBLK1 512
#define NTHR1 256

__global__ void k0_zero(float* __restrict__ acc)
{
    int i = blockIdx.x * 256 + threadIdx.x;
    if (i < ACCSZ) acc[i] = 0.f;
}

__global__ __launch_bounds__(NTHR1, 2) void k1_accum(
    const float* __restrict__ in, const int* __restrict__ tgt,
    float* __restrict__ acc)
{
    __shared__ float lds[NCOPY * ACCSZ];   // 4940 floats = 19760 B
    const int t = threadIdx.x;

    for (int i = t; i < NCOPY * ACCSZ; i += NTHR1) lds[i] = 0.f;
    __syncthreads();

    float* my = lds + (t & (NCOPY - 1)) * ACCSZ;

    const long long T = (long long)NBLK1 * NTHR1;     // 131072 threads
    const long long NPAIR = NPIX / 2;                 // 1048576 pixel-pairs
    long long tid = (long long)blockIdx.x * NTHR1 + t;

    for (long long p = tid; p < NPAIR; p += T) {
        long long n0 = 2 * p;
        int b  = (int)(n0 >> 18);
        int hw = (int)(n0 & (HWSZ - 1));
        const float* base = in + ((size_t)b * DD) * HWSZ + hw;

        int2 lab = *(const int2*)(tgt + n0);   // int32 labels, 8B aligned
        int c0 = lab.x;
        int c1 = lab.y;

        float2 v[DD];
        float ss0 = 0.f, ss1 = 0.f;
        #pragma unroll
        for (int d = 0; d < DD; d++) {
            float2 x = *(const float2*)(base + ((size_t)d << 18));
            v[d] = x;
            ss0 = fmaf(x.x, x.x, ss0);
            ss1 = fmaf(x.y, x.y, ss1);
        }
        float inv0 = rsqrtf(fmaxf(ss0, 1e-30f));
        float inv1 = rsqrtf(fmaxf(ss1, 1e-30f));

        float* a0 = my + c0 * CSTRIDE;
        #pragma unroll
        for (int d = 0; d < DD; d++) {
            atomicAdd(a0 + d,      v[d].x);
            atomicAdd(a0 + 32 + d, v[d].x * inv0);
        }
        atomicAdd(a0 + 64, 1.f);

        float* a1 = my + c1 * CSTRIDE;
        #pragma unroll
        for (int d = 0; d < DD; d++) {
            atomicAdd(a1 + d,      v[d].y);
            atomicAdd(a1 + 32 + d, v[d].y * inv1);
        }
        atomicAdd(a1 + 64, 1.f);
    }
    __syncthreads();

    // fold 4 LDS copies -> device-scope atomic add into the global accumulator
    for (int i = t; i < ACCSZ; i += NTHR1) {
        float s = (lds[i] + lds[ACCSZ + i]) + (lds[2 * ACCSZ + i] + lds[3 * ACCSZ + i]);
        atomicAdd(acc + i, s);
    }
}

// Final: tiny 19-class epilogue. 1 block x 256 threads.
__global__ void k3_final(const float* __restrict__ gacc, float* __restrict__ out)
{
    __shared__ float acc[ACCSZ];
    __shared__ float cn[CC];
    __shared__ float pres[CC];
    __shared__ float res;
    const int t = threadIdx.x;

    for (int i = t; i < ACCSZ; i += 256) acc[i] = gacc[i];
    if (t == 0) res = 0.f;
    __syncthreads();

    // per-class: norms, presence, sim term
    // cosine is scale-invariant in the center, so raw sums replace centers:
    // seg_cos_c = (sums_c . S_c) / |sums_c|,  S_c = sum_{n in c} x_n/|x_n|
    if (t < CC) {
        const float* a = acc + t * CSTRIDE;
        float n2 = 0.f, dotS = 0.f;
        #pragma unroll
        for (int d = 0; d < DD; d++) {
            n2   = fmaf(a[d], a[d], n2);
            dotS = fmaf(a[d], a[32 + d], dotS);
        }
        float count = a[64];
        float den   = fmaxf(count, 1.f);
        float norm  = sqrtf(n2);
        cn[t]   = norm;
        pres[t] = (count > 0.f) ? 1.f : 0.f;
        float segcos  = (norm > 0.f) ? (dotS / norm) : 0.f;
        float simterm = (count > 0.f) ? (1.f - segcos / den) : 0.f;
        atomicAdd(&res, simterm);
    }
    __syncthreads();

    // diff loss: 19x19 pair terms on raw sums (dens cancel in cosine)
    for (int p = t; p < CC * CC; p += 256) {
        int i = p / CC, j = p % CC;
        const float* ai = acc + i * CSTRIDE;
        const float* aj = acc + j * CSTRIDE;
        float dot = 0.f;
        #pragma unroll
        for (int d = 0; d < DD; d++) dot = fmaf(ai[d], aj[d], dot);
        float dd  = fmaxf(cn[i] * cn[j], EPSF);
        float cs  = dot / dd;
        float term = (i == j) ? (1.f - cs) : fmaxf(cs, 0.f);
        atomicAdd(&res, pres[i] * term * (1.f / (float)CC));
    }
    __syncthreads();
    if (t == 0) out[0] = res;
}

extern "C" void kernel_launch(void* const* d_in, const int* in_sizes, int n_in,
                              void* d_out, int out_size, void* d_ws, size_t ws_size,
                              hipStream_t stream)
{
    const float* in  = (const float*)d_in[0];
    const int*   tgt = (const int*)d_in[1];   // harness delivers integer inputs as int32
    float* out = (float*)d_out;
    float* acc = (float*)d_ws;                // 1235 floats ~ 5 KB

    hipLaunchKernelGGL(k0_zero, dim3((ACCSZ + 255) / 256), dim3(256), 0, stream, acc);
    hipLaunchKernelGGL(k1_accum, dim3(NBLK1), dim3(NTHR1), 0, stream, in, tgt, acc);
    hipLaunchKernelGGL(k3_final, dim3(1), dim3(256), 0, stream, acc, out);
}

// Round 3
// 949.980 us; speedup vs baseline: 1.0048x; 1.0048x over previous
//
#include <hip/hip_runtime.h>

// Problem constants (fixed by setup_inputs)
#define BB 8
#define DD 32
#define HH 512
#define WW 512
#define HWSZ (HH*WW)          // 262144 = 2^18
#define NPIX (BB*HWSZ)        // 2097152
#define CC 19
#define EPSF 1e-8f

// Accumulator layout: per class 65 floats: [0..31]=sum(x), [32..63]=sum(x/|x|), [64]=count
#define CSTRIDE 65
#define ACCSZ (CC*CSTRIDE)    // 1235 floats = 4940 B  (total ws footprint)
#define NCOPY 8               // LDS copies: 8 lanes/copy -> low same-address multiplicity

#define NBLK1 1024
#define NTHR1 256

__global__ void k0_zero(float* __restrict__ acc)
{
    int i = blockIdx.x * 256 + threadIdx.x;
    if (i < ACCSZ) acc[i] = 0.f;
}

__global__ __launch_bounds__(NTHR1, 4) void k1_accum(
    const float* __restrict__ in, const int* __restrict__ tgt,
    float* __restrict__ acc)
{
    __shared__ float lds[NCOPY * ACCSZ];   // 9880 floats = 39520 B -> 4 blocks/CU
    const int t = threadIdx.x;

    for (int i = t; i < NCOPY * ACCSZ; i += NTHR1) lds[i] = 0.f;
    __syncthreads();

    float* my = lds + (t & (NCOPY - 1)) * ACCSZ;

    const long long T = (long long)NBLK1 * NTHR1;     // 262144 threads
    const long long NPAIR = NPIX / 2;                 // 1048576 pixel-pairs -> 4 per thread
    long long tid = (long long)blockIdx.x * NTHR1 + t;

    for (long long p = tid; p < NPAIR; p += T) {
        long long n0 = 2 * p;
        int b  = (int)(n0 >> 18);
        int hw = (int)(n0 & (HWSZ - 1));
        const float* base = in + ((size_t)b * DD) * HWSZ + hw;

        int2 lab = *(const int2*)(tgt + n0);   // int32 labels, 8B aligned
        int c0 = lab.x;
        int c1 = lab.y;

        float2 v[DD];
        float ss0 = 0.f, ss1 = 0.f;
        #pragma unroll
        for (int d = 0; d < DD; d++) {
            float2 x = *(const float2*)(base + ((size_t)d << 18));
            v[d] = x;
            ss0 = fmaf(x.x, x.x, ss0);
            ss1 = fmaf(x.y, x.y, ss1);
        }
        float inv0 = rsqrtf(fmaxf(ss0, 1e-30f));
        float inv1 = rsqrtf(fmaxf(ss1, 1e-30f));

        // fire-and-forget HW fp atomics (ds_add_f32) — no dependent waitcnt
        float* a0 = my + c0 * CSTRIDE;
        #pragma unroll
        for (int d = 0; d < DD; d++) {
            unsafeAtomicAdd(a0 + d,      v[d].x);
            unsafeAtomicAdd(a0 + 32 + d, v[d].x * inv0);
        }
        unsafeAtomicAdd(a0 + 64, 1.f);

        float* a1 = my + c1 * CSTRIDE;
        #pragma unroll
        for (int d = 0; d < DD; d++) {
            unsafeAtomicAdd(a1 + d,      v[d].y);
            unsafeAtomicAdd(a1 + 32 + d, v[d].y * inv1);
        }
        unsafeAtomicAdd(a1 + 64, 1.f);
    }
    __syncthreads();

    // fold 8 LDS copies -> device-scope HW atomic add into the global accumulator
    for (int i = t; i < ACCSZ; i += NTHR1) {
        float s = 0.f;
        #pragma unroll
        for (int k = 0; k < NCOPY; k++) s += lds[k * ACCSZ + i];
        unsafeAtomicAdd(acc + i, s);
    }
}

// Final: tiny 19-class epilogue. 1 block x 256 threads, deterministic reduction.
__global__ void k3_final(const float* __restrict__ gacc, float* __restrict__ out)
{
    __shared__ float acc[ACCSZ];
    __shared__ float cn[CC];
    __shared__ float pres[CC];
    __shared__ float red[256];
    const int t = threadIdx.x;

    for (int i = t; i < ACCSZ; i += 256) acc[i] = gacc[i];
    __syncthreads();

    float part = 0.f;

    // per-class: norms, presence, sim term
    // cosine is scale-invariant in the center, so raw sums replace centers:
    // seg_cos_c = (sums_c . S_c) / |sums_c|,  S_c = sum_{n in c} x_n/|x_n|
    if (t < CC) {
        const float* a = acc + t * CSTRIDE;
        float n2 = 0.f, dotS = 0.f;
        #pragma unroll
        for (int d = 0; d < DD; d++) {
            n2   = fmaf(a[d], a[d], n2);
            dotS = fmaf(a[d], a[32 + d], dotS);
        }
        float count = a[64];
        float den   = fmaxf(count, 1.f);
        float norm  = sqrtf(n2);
        cn[t]   = norm;
        pres[t] = (count > 0.f) ? 1.f : 0.f;
        float segcos = (norm > 0.f) ? (dotS / norm) : 0.f;
        part += (count > 0.f) ? (1.f - segcos / den) : 0.f;
    }
    __syncthreads();

    // diff loss: 19x19 pair terms on raw sums (denominators cancel in cosine)
    for (int p = t; p < CC * CC; p += 256) {
        int i = p / CC, j = p % CC;
        const float* ai = acc + i * CSTRIDE;
        const float* aj = acc + j * CSTRIDE;
        float dot = 0.f;
        #pragma unroll
        for (int d = 0; d < DD; d++) dot = fmaf(ai[d], aj[d], dot);
        float dd  = fmaxf(cn[i] * cn[j], EPSF);
        float cs  = dot / dd;
        float term = (i == j) ? (1.f - cs) : fmaxf(cs, 0.f);
        part += pres[i] * term * (1.f / (float)CC);
    }

    red[t] = part;
    __syncthreads();
    // deterministic halving tree
    #pragma unroll
    for (int s = 128; s > 0; s >>= 1) {
        if (t < s) red[t] += red[t + s];
        __syncthreads();
    }
    if (t == 0) out[0] = red[0];
}

extern "C" void kernel_launch(void* const* d_in, const int* in_sizes, int n_in,
                              void* d_out, int out_size, void* d_ws, size_t ws_size,
                              hipStream_t stream)
{
    const float* in  = (const float*)d_in[0];
    const int*   tgt = (const int*)d_in[1];   // harness delivers integer inputs as int32
    float* out = (float*)d_out;
    float* acc = (float*)d_ws;                // 1235 floats ~ 5 KB

    hipLaunchKernelGGL(k0_zero, dim3((ACCSZ + 255) / 256), dim3(256), 0, stream, acc);
    hipLaunchKernelGGL(k1_accum, dim3(NBLK1), dim3(NTHR1), 0, stream, in, tgt, acc);
    hipLaunchKernelGGL(k3_final, dim3(1), dim3(256), 0, stream, acc, out);
}